// Round 1
// baseline (933.346 us; speedup 1.0000x reference)
//
#include <hip/hip_runtime.h>
#include <cstdint>

#define HH 4
#define DD 32
#define HID 128
#define FE 16
#define NEG 0.2f

// ----------------------------- small utils -----------------------------
__global__ void k_zero_i32(int* __restrict__ p, int n) {
  int i = blockIdx.x * blockDim.x + threadIdx.x;
  if (i < n) p[i] = 0;
}

// ----------------------------- CSR build -----------------------------
__global__ void k_hist(const int* __restrict__ dst, int* __restrict__ cnt, int E) {
  int i = blockIdx.x * blockDim.x + threadIdx.x;
  if (i < E) atomicAdd(&cnt[dst[i]], 1);
}

// in-place inclusive scan per 256-block + per-block sums
__global__ void k_scanA(int* __restrict__ cnt, int* __restrict__ bsum, int N) {
  __shared__ int sh[256];
  int t = threadIdx.x, i = blockIdx.x * 256 + t;
  int v = (i < N) ? cnt[i] : 0;
  sh[t] = v;
  __syncthreads();
  for (int off = 1; off < 256; off <<= 1) {
    int add = (t >= off) ? sh[t - off] : 0;
    __syncthreads();
    sh[t] += add;
    __syncthreads();
  }
  if (i < N) cnt[i] = sh[t];
  if (t == 255) bsum[blockIdx.x] = sh[255];
}

// single block: exclusive scan of block sums (nb <= 256)
__global__ void k_scanB(int* __restrict__ bsum, int nb) {
  __shared__ int sh[256];
  int t = threadIdx.x;
  int v = (t < nb) ? bsum[t] : 0;
  sh[t] = v;
  __syncthreads();
  for (int off = 1; off < 256; off <<= 1) {
    int add = (t >= off) ? sh[t - off] : 0;
    __syncthreads();
    sh[t] += add;
    __syncthreads();
  }
  if (t < nb) bsum[t] = sh[t] - v;  // exclusive
}

__global__ void k_scanC(const int* __restrict__ cnt, const int* __restrict__ bsum,
                        int* __restrict__ rowptr, int N) {
  int i = blockIdx.x * blockDim.x + threadIdx.x;
  if (i < N) rowptr[i + 1] = cnt[i] + bsum[i >> 8];
  if (i == 0) rowptr[0] = 0;
}

__global__ void k_scatter(const int* __restrict__ dst, const int* __restrict__ rowptr,
                          int* __restrict__ fill, int* __restrict__ eidx, int E) {
  int i = blockIdx.x * blockDim.x + threadIdx.x;
  if (i < E) {
    int d = dst[i];
    int pos = rowptr[d] + atomicAdd(&fill[d], 1);
    eidx[pos] = i;
  }
}

// ----------------------------- tiny V projections -----------------------------
// V[k][h] = sum_d W[k, h*32+d] * a[h, d]   (V stored [K][4] row-major)
struct VJob { const float* W; const float* a; float* V; int K; };
struct VJobs { VJob j[6]; };

__global__ void k_makev(VJobs P) {
  VJob job = P.j[blockIdx.x];
  int t = threadIdx.x;  // 128 threads
  if (t < job.K) {
    for (int h = 0; h < HH; ++h) {
      const float* wrow = job.W + t * HID + h * DD;
      const float* ar = job.a + h * DD;
      float s = 0.f;
      for (int d = 0; d < DD; ++d) s += wrow[d] * ar[d];
      job.V[t * HH + h] = s;
    }
  }
}

// P[n][0:4] = X[n] @ Vl, P[n][4:8] = X[n] @ Vr
__global__ void k_proj(const float* __restrict__ X, const float* __restrict__ Vl,
                       const float* __restrict__ Vr, float* __restrict__ P, int N) {
  int idx = blockIdx.x * blockDim.x + threadIdx.x;
  if (idx >= N * 8) return;
  int n = idx >> 3, j = idx & 7;
  const float* V = (j < 4) ? Vl : Vr;
  int jj = j & 3;
  const float4* x4 = (const float4*)(X + (size_t)n * HID);
  float acc = 0.f;
#pragma unroll 8
  for (int k4 = 0; k4 < 32; ++k4) {
    float4 x = x4[k4];
    acc += x.x * V[(k4 * 4 + 0) * 4 + jj];
    acc += x.y * V[(k4 * 4 + 1) * 4 + jj];
    acc += x.z * V[(k4 * 4 + 2) * 4 + jj];
    acc += x.w * V[(k4 * 4 + 3) * 4 + jj];
  }
  P[idx] = acc;
}

// ee[e][h] = Ef[e, 0:16] @ Ve[16][4]
__global__ void k_ee(const float* __restrict__ Ef, const float* __restrict__ Ve,
                     float* __restrict__ ee, int E) {
  int e = blockIdx.x * blockDim.x + threadIdx.x;
  if (e >= E) return;
  const float4* f4 = (const float4*)(Ef + (size_t)e * FE);
  float a0 = 0.f, a1 = 0.f, a2 = 0.f, a3 = 0.f;
#pragma unroll
  for (int k4 = 0; k4 < 4; ++k4) {
    float4 x = f4[k4];
    const float* v = Ve + k4 * 16;
    a0 += x.x * v[0] + x.y * v[4] + x.z * v[8]  + x.w * v[12];
    a1 += x.x * v[1] + x.y * v[5] + x.z * v[9]  + x.w * v[13];
    a2 += x.x * v[2] + x.y * v[6] + x.z * v[10] + x.w * v[14];
    a3 += x.x * v[3] + x.y * v[7] + x.z * v[11] + x.w * v[15];
  }
  ((float4*)ee)[e] = make_float4(a0, a1, a2, a3);
}

// ----------------------------- fs GEMM (f32) -----------------------------
// out[N,128] = X[N,128] @ W[128,128]; tile BM=64 rows, K chunked by 64.
#define BM 64
#define KC 64
__global__ __launch_bounds__(256) void k_gemm(const float* __restrict__ X,
                                              const float* __restrict__ W,
                                              float* __restrict__ out, int N) {
  __shared__ float Xs[BM * KC];    // 16 KB
  __shared__ float Ws[KC * HID];   // 32 KB
  int t = threadIdx.x;
  int bm = blockIdx.x * BM;
  int rg = t >> 5;   // 0..7 -> 8 rows each
  int cg = t & 31;   // 0..31 -> 4 cols each
  float acc[8][4] = {};
  for (int kc = 0; kc < HID; kc += KC) {
    // stage X tile: 64x64 floats
    for (int i = t; i < BM * KC / 4; i += 256) {
      int r = i / (KC / 4);
      int c4 = i % (KC / 4);
      int gr = bm + r;
      if (gr >= N) gr = N - 1;
      ((float4*)Xs)[r * (KC / 4) + c4] = *(const float4*)(X + (size_t)gr * HID + kc + c4 * 4);
    }
    // stage W tile: 64x128 floats
    for (int i = t; i < KC * HID / 4; i += 256) {
      ((float4*)Ws)[i] = *(const float4*)(W + kc * HID + i * 4);
    }
    __syncthreads();
#pragma unroll 8
    for (int k = 0; k < KC; ++k) {
      float b0 = Ws[k * HID + cg * 4 + 0];
      float b1 = Ws[k * HID + cg * 4 + 1];
      float b2 = Ws[k * HID + cg * 4 + 2];
      float b3 = Ws[k * HID + cg * 4 + 3];
#pragma unroll
      for (int i = 0; i < 8; ++i) {
        float a = Xs[(rg * 8 + i) * KC + k];
        acc[i][0] += a * b0;
        acc[i][1] += a * b1;
        acc[i][2] += a * b2;
        acc[i][3] += a * b3;
      }
    }
    __syncthreads();
  }
#pragma unroll
  for (int i = 0; i < 8; ++i) {
    int gr = bm + rg * 8 + i;
    if (gr < N)
      *(float4*)(out + (size_t)gr * HID + cg * 4) =
          make_float4(acc[i][0], acc[i][1], acc[i][2], acc[i][3]);
  }
}

// ----------------------------- per-dst aggregation -----------------------------
// one wave per destination node; lane = head*16 + slot; slot covers 2 d-elements.
template <bool RELU>
__global__ __launch_bounds__(256) void k_agg(
    const int* __restrict__ rowptr, const int* __restrict__ eidx, const int* __restrict__ src,
    const float* __restrict__ Psrc, const float* __restrict__ Pdst,
    const float* __restrict__ ee, const float* __restrict__ fs,
    float* __restrict__ out, int N) {
  int wid = threadIdx.x >> 6;
  int lane = threadIdx.x & 63;
  int n = blockIdx.x * 4 + wid;
  if (n >= N) return;
  int h = lane >> 4, tt = lane & 15;
  int base = rowptr[n], end = rowptr[n + 1];
  float er = Pdst[n * 8 + 4 + h];
  float m = -3.0e38f, s = 0.f, a0 = 0.f, a1 = 0.f;
  for (int j = base; j < end; ++j) {
    int e = eidx[j];
    int sn = src[e];
    float x = Psrc[sn * 8 + h] + er + ee[e * 4 + h];
    x = (x > 0.f) ? x : NEG * x;
    float2 f = *(const float2*)(fs + (size_t)sn * HID + h * DD + tt * 2);
    float mn = fmaxf(m, x);
    float sc = __expf(m - mn);   // 0 on first edge (m = -3e38)
    float w = __expf(x - mn);
    s = s * sc + w;
    a0 = a0 * sc + w * f.x;
    a1 = a1 * sc + w * f.y;
    m = mn;
  }
  float inv = 1.f / (s + 1e-9f);
  a0 *= inv;
  a1 *= inv;
  if (RELU) { a0 = fmaxf(a0, 0.f); a1 = fmaxf(a1, 0.f); }
  *(float2*)(out + (size_t)n * HID + h * DD + tt * 2) = make_float2(a0, a1);
}

// ----------------------------- host side -----------------------------
extern "C" void kernel_launch(void* const* d_in, const int* in_sizes, int n_in,
                              void* d_out, int out_size, void* d_ws, size_t ws_size,
                              hipStream_t stream) {
  const float* X_user = (const float*)d_in[0];
  const float* X_item = (const float*)d_in[1];
  const float* Ef_ui[2] = {(const float*)d_in[2], (const float*)d_in[4]};
  const float* Ef_iu[2] = {(const float*)d_in[3], (const float*)d_in[5]};
  // weight groups: base 6 + (l*2 + et)*5 ; et: 0=ui, 1=iu ; within: W, We, al, ar, ae
  const float* Wp[2][2];  const float* Wep[2][2];
  const float* alp[2][2]; const float* arp[2][2]; const float* aep[2][2];
  for (int l = 0; l < 2; ++l)
    for (int et = 0; et < 2; ++et) {
      int b = 6 + (l * 2 + et) * 5;
      Wp[l][et]  = (const float*)d_in[b + 0];
      Wep[l][et] = (const float*)d_in[b + 1];
      alp[l][et] = (const float*)d_in[b + 2];
      arp[l][et] = (const float*)d_in[b + 3];
      aep[l][et] = (const float*)d_in[b + 4];
    }
  const int* src_ui = (const int*)d_in[26];
  const int* dst_ui = (const int*)d_in[27];
  const int* src_iu = (const int*)d_in[28];
  const int* dst_iu = (const int*)d_in[29];

  const int N = in_sizes[0] / HID;  // 50000
  const int E = in_sizes[26];       // 500000

  // ---- workspace carve-up ----
  char* w = (char*)d_ws;
  size_t off = 0;
  auto carve = [&](size_t bytes) {
    off = (off + 255) & ~(size_t)255;
    char* p = w + off;
    off += bytes;
    return p;
  };
  int* rowptr_ui = (int*)carve((N + 1) * 4);
  int* rowptr_iu = (int*)carve((N + 1) * 4);
  int* eidx_ui = (int*)carve((size_t)E * 4);
  int* eidx_iu = (int*)carve((size_t)E * 4);
  int* cnt_blk = (int*)carve((size_t)4 * N * 4);  // cnt_ui | cnt_iu | fill_ui | fill_iu
  int* cnt_ui = cnt_blk, *cnt_iu = cnt_blk + N, *fill_ui = cnt_blk + 2 * N, *fill_iu = cnt_blk + 3 * N;
  int* bsum_ui = (int*)carve(256 * 4);
  int* bsum_iu = (int*)carve(256 * 4);
  float* P_user = (float*)carve((size_t)N * 8 * 4);
  float* P_item = (float*)carve((size_t)N * 8 * 4);
  float* ee_ui = (float*)carve((size_t)E * 4 * 4);
  float* ee_iu = (float*)carve((size_t)E * 4 * 4);
  float* fs_a = (float*)carve((size_t)N * HID * 4);  // src-proj for ui graph
  float* fs_b = (float*)carve((size_t)N * HID * 4);  // src-proj for iu graph
  float* h_u1 = (float*)carve((size_t)N * HID * 4);
  float* h_i1 = (float*)carve((size_t)N * HID * 4);
  float* Vl_u = (float*)carve(HID * 4 * 4);
  float* Vr_u = (float*)carve(HID * 4 * 4);
  float* Vl_i = (float*)carve(HID * 4 * 4);
  float* Vr_i = (float*)carve(HID * 4 * 4);
  float* Ve_ui = (float*)carve(FE * 4 * 4);
  float* Ve_iu = (float*)carve(FE * 4 * 4);

  const int nbE = (E + 255) / 256;
  const int nbN = (N + 255) / 256;  // 196

  // ---- CSR build (once; shared by both layers) ----
  k_zero_i32<<<(4 * N + 255) / 256, 256, 0, stream>>>(cnt_blk, 4 * N);
  k_hist<<<nbE, 256, 0, stream>>>(dst_ui, cnt_ui, E);
  k_hist<<<nbE, 256, 0, stream>>>(dst_iu, cnt_iu, E);
  k_scanA<<<nbN, 256, 0, stream>>>(cnt_ui, bsum_ui, N);
  k_scanA<<<nbN, 256, 0, stream>>>(cnt_iu, bsum_iu, N);
  k_scanB<<<1, 256, 0, stream>>>(bsum_ui, nbN);
  k_scanB<<<1, 256, 0, stream>>>(bsum_iu, nbN);
  k_scanC<<<nbN, 256, 0, stream>>>(cnt_ui, bsum_ui, rowptr_ui, N);
  k_scanC<<<nbN, 256, 0, stream>>>(cnt_iu, bsum_iu, rowptr_iu, N);
  k_scatter<<<nbE, 256, 0, stream>>>(dst_ui, rowptr_ui, fill_ui, eidx_ui, E);
  k_scatter<<<nbE, 256, 0, stream>>>(dst_iu, rowptr_iu, fill_iu, eidx_iu, E);

  // ---- layers ----
  for (int l = 0; l < 2; ++l) {
    const float* Xu = (l == 0) ? X_user : h_u1;
    const float* Xi = (l == 0) ? X_item : h_i1;
    // ui graph uses W_ui (et=0): fs = Xu@W_ui, fd·ar = Xi@(W_ui·ar_ui)
    // iu graph uses W_iu (et=1): fs = Xi@W_iu, fd·ar = Xu@(W_iu·ar_iu)
    VJobs jb;
    jb.j[0] = {Wp[l][0], alp[l][0], Vl_u, HID};  // el for users as src (ui)
    jb.j[1] = {Wp[l][1], arp[l][1], Vr_u, HID};  // er for users as dst (iu)
    jb.j[2] = {Wp[l][1], alp[l][1], Vl_i, HID};  // el for items as src (iu)
    jb.j[3] = {Wp[l][0], arp[l][0], Vr_i, HID};  // er for items as dst (ui)
    jb.j[4] = {Wep[l][0], aep[l][0], Ve_ui, FE};
    jb.j[5] = {Wep[l][1], aep[l][1], Ve_iu, FE};
    k_makev<<<6, 128, 0, stream>>>(jb);

    k_proj<<<(N * 8 + 255) / 256, 256, 0, stream>>>(Xu, Vl_u, Vr_u, P_user, N);
    k_proj<<<(N * 8 + 255) / 256, 256, 0, stream>>>(Xi, Vl_i, Vr_i, P_item, N);
    k_ee<<<nbE, 256, 0, stream>>>(Ef_ui[l], Ve_ui, ee_ui, E);
    k_ee<<<nbE, 256, 0, stream>>>(Ef_iu[l], Ve_iu, ee_iu, E);
    k_gemm<<<(N + BM - 1) / BM, 256, 0, stream>>>(Xu, Wp[l][0], fs_a, N);
    k_gemm<<<(N + BM - 1) / BM, 256, 0, stream>>>(Xi, Wp[l][1], fs_b, N);

    float* out_ui = (l == 0) ? h_i1 : ((float*)d_out + (size_t)N * HID);  // hi2 second
    float* out_iu = (l == 0) ? h_u1 : (float*)d_out;                      // hu2 first
    int aggGrid = (N + 3) / 4;
    if (l == 0) {
      k_agg<true><<<aggGrid, 256, 0, stream>>>(rowptr_ui, eidx_ui, src_ui, P_user, P_item,
                                               ee_ui, fs_a, out_ui, N);
      k_agg<true><<<aggGrid, 256, 0, stream>>>(rowptr_iu, eidx_iu, src_iu, P_item, P_user,
                                               ee_iu, fs_b, out_iu, N);
    } else {
      k_agg<false><<<aggGrid, 256, 0, stream>>>(rowptr_ui, eidx_ui, src_ui, P_user, P_item,
                                                ee_ui, fs_a, out_ui, N);
      k_agg<false><<<aggGrid, 256, 0, stream>>>(rowptr_iu, eidx_iu, src_iu, P_item, P_user,
                                                ee_iu, fs_b, out_iu, N);
    }
  }
}

// Round 2
// 763.280 us; speedup vs baseline: 1.2228x; 1.2228x over previous
//
#include <hip/hip_runtime.h>
#include <cstdint>

#define HH 4
#define DD 32
#define HID 128
#define FE 16
#define NEG 0.2f

// ----------------------------- small utils -----------------------------
__global__ void k_zero_i32(int* __restrict__ p, int n) {
  int i = blockIdx.x * blockDim.x + threadIdx.x;
  if (i < n) p[i] = 0;
}

__device__ inline unsigned short f2b(float x) {  // f32 -> bf16 RNE
  unsigned int u = __float_as_uint(x);
  u = (u + 0x7fffu + ((u >> 16) & 1u)) >> 16;
  return (unsigned short)u;
}
__device__ inline float b2f(unsigned short b) {
  return __uint_as_float(((unsigned int)b) << 16);
}

// ----------------------------- CSR build -----------------------------
__global__ void k_hist(const int* __restrict__ dst, int* __restrict__ cnt, int E) {
  int i = blockIdx.x * blockDim.x + threadIdx.x;
  if (i < E) atomicAdd(&cnt[dst[i]], 1);
}

// in-place inclusive scan per 256-block + per-block sums
__global__ void k_scanA(int* __restrict__ cnt, int* __restrict__ bsum, int N) {
  __shared__ int sh[256];
  int t = threadIdx.x, i = blockIdx.x * 256 + t;
  int v = (i < N) ? cnt[i] : 0;
  sh[t] = v;
  __syncthreads();
  for (int off = 1; off < 256; off <<= 1) {
    int add = (t >= off) ? sh[t - off] : 0;
    __syncthreads();
    sh[t] += add;
    __syncthreads();
  }
  if (i < N) cnt[i] = sh[t];
  if (t == 255) bsum[blockIdx.x] = sh[255];
}

// single block: exclusive scan of block sums (nb <= 256)
__global__ void k_scanB(int* __restrict__ bsum, int nb) {
  __shared__ int sh[256];
  int t = threadIdx.x;
  int v = (t < nb) ? bsum[t] : 0;
  sh[t] = v;
  __syncthreads();
  for (int off = 1; off < 256; off <<= 1) {
    int add = (t >= off) ? sh[t - off] : 0;
    __syncthreads();
    sh[t] += add;
    __syncthreads();
  }
  if (t < nb) bsum[t] = sh[t] - v;  // exclusive
}

__global__ void k_scanC(const int* __restrict__ cnt, const int* __restrict__ bsum,
                        int* __restrict__ rowptr, int N) {
  int i = blockIdx.x * blockDim.x + threadIdx.x;
  if (i < N) rowptr[i + 1] = cnt[i] + bsum[i >> 8];
  if (i == 0) rowptr[0] = 0;
}

// scatter edge ids AND source node ids into CSR order
__global__ void k_scatter(const int* __restrict__ dst, const int* __restrict__ src,
                          const int* __restrict__ rowptr, int* __restrict__ fill,
                          int* __restrict__ eidx, int* __restrict__ srcs, int E) {
  int i = blockIdx.x * blockDim.x + threadIdx.x;
  if (i < E) {
    int d = dst[i];
    int pos = rowptr[d] + atomicAdd(&fill[d], 1);
    eidx[pos] = i;
    srcs[pos] = src[i];
  }
}

// ----------------------------- tiny V projections -----------------------------
// V[k][h] = sum_d W[k, h*32+d] * a[h, d]   (V stored [K][4] row-major)
struct VJob { const float* W; const float* a; float* V; int K; };
struct VJobs { VJob j[6]; };

__global__ void k_makev(VJobs P) {
  VJob job = P.j[blockIdx.x];
  int t = threadIdx.x;  // 128 threads
  if (t < job.K) {
    for (int h = 0; h < HH; ++h) {
      const float* wrow = job.W + t * HID + h * DD;
      const float* ar = job.a + h * DD;
      float s = 0.f;
      for (int d = 0; d < DD; ++d) s += wrow[d] * ar[d];
      job.V[t * HH + h] = s;
    }
  }
}

// P[n][0:4] = X[n] @ Vl, P[n][4:8] = X[n] @ Vr
__global__ void k_proj(const float* __restrict__ X, const float* __restrict__ Vl,
                       const float* __restrict__ Vr, float* __restrict__ P, int N) {
  int idx = blockIdx.x * blockDim.x + threadIdx.x;
  if (idx >= N * 8) return;
  int n = idx >> 3, j = idx & 7;
  const float* V = (j < 4) ? Vl : Vr;
  int jj = j & 3;
  const float4* x4 = (const float4*)(X + (size_t)n * HID);
  float acc = 0.f;
#pragma unroll 8
  for (int k4 = 0; k4 < 32; ++k4) {
    float4 x = x4[k4];
    acc += x.x * V[(k4 * 4 + 0) * 4 + jj];
    acc += x.y * V[(k4 * 4 + 1) * 4 + jj];
    acc += x.z * V[(k4 * 4 + 2) * 4 + jj];
    acc += x.w * V[(k4 * 4 + 3) * 4 + jj];
  }
  P[idx] = acc;
}

// eec[j][h] = Ef[eidx[j], 0:16] @ Ve[16][4]   (CSR order)
__global__ void k_ee(const float* __restrict__ Ef, const float* __restrict__ Ve,
                     const int* __restrict__ eidx, float* __restrict__ eec, int E) {
  int j = blockIdx.x * blockDim.x + threadIdx.x;
  if (j >= E) return;
  int e = eidx[j];
  const float4* f4 = (const float4*)(Ef + (size_t)e * FE);
  float a0 = 0.f, a1 = 0.f, a2 = 0.f, a3 = 0.f;
#pragma unroll
  for (int k4 = 0; k4 < 4; ++k4) {
    float4 x = f4[k4];
    const float* v = Ve + k4 * 16;
    a0 += x.x * v[0] + x.y * v[4] + x.z * v[8]  + x.w * v[12];
    a1 += x.x * v[1] + x.y * v[5] + x.z * v[9]  + x.w * v[13];
    a2 += x.x * v[2] + x.y * v[6] + x.z * v[10] + x.w * v[14];
    a3 += x.x * v[3] + x.y * v[7] + x.z * v[11] + x.w * v[15];
  }
  ((float4*)eec)[j] = make_float4(a0, a1, a2, a3);
}

// ----------------------------- fs GEMM (f32 math, bf16 out) -----------------------------
// out[N,128](bf16) = X[N,128] @ W[128,128]; tile BM=64 rows, K chunked by 64.
#define BM 64
#define KC 64
__global__ __launch_bounds__(256) void k_gemm(const float* __restrict__ X,
                                              const float* __restrict__ W,
                                              unsigned short* __restrict__ outb, int N) {
  __shared__ float Xs[BM * KC];    // 16 KB
  __shared__ float Ws[KC * HID];   // 32 KB
  int t = threadIdx.x;
  int bm = blockIdx.x * BM;
  int rg = t >> 5;   // 0..7 -> 8 rows each
  int cg = t & 31;   // cols cg, cg+32, cg+64, cg+96  (bank-conflict-free)
  float acc[8][4] = {};
  for (int kc = 0; kc < HID; kc += KC) {
    for (int i = t; i < BM * KC / 4; i += 256) {
      int r = i / (KC / 4);
      int c4 = i % (KC / 4);
      int gr = bm + r;
      if (gr >= N) gr = N - 1;
      ((float4*)Xs)[r * (KC / 4) + c4] = *(const float4*)(X + (size_t)gr * HID + kc + c4 * 4);
    }
    for (int i = t; i < KC * HID / 4; i += 256) {
      ((float4*)Ws)[i] = *(const float4*)(W + kc * HID + i * 4);
    }
    __syncthreads();
#pragma unroll 8
    for (int k = 0; k < KC; ++k) {
      float b0 = Ws[k * HID + cg];
      float b1 = Ws[k * HID + cg + 32];
      float b2 = Ws[k * HID + cg + 64];
      float b3 = Ws[k * HID + cg + 96];
#pragma unroll
      for (int i = 0; i < 8; ++i) {
        float a = Xs[(rg * 8 + i) * KC + k];
        acc[i][0] += a * b0;
        acc[i][1] += a * b1;
        acc[i][2] += a * b2;
        acc[i][3] += a * b3;
      }
    }
    __syncthreads();
  }
#pragma unroll
  for (int i = 0; i < 8; ++i) {
    int gr = bm + rg * 8 + i;
    if (gr < N) {
      unsigned short* o = outb + (size_t)gr * HID;
      o[cg]      = f2b(acc[i][0]);
      o[cg + 32] = f2b(acc[i][1]);
      o[cg + 64] = f2b(acc[i][2]);
      o[cg + 96] = f2b(acc[i][3]);
    }
  }
}

// ----------------------------- per-dst aggregation -----------------------------
// one wave per destination node; half-wave per edge (2 edges/iter).
// lane L=lane&31 owns elems 4L..4L+3 (head h=L>>3); no max-tracking (logits |x|<~6).
template <bool RELU>
__global__ __launch_bounds__(256) void k_agg(
    const int* __restrict__ rowptr, const int* __restrict__ srcs,
    const float* __restrict__ Psrc, const float* __restrict__ Pdst,
    const float* __restrict__ eec, const unsigned short* __restrict__ fsb,
    float* __restrict__ out, int N) {
  int wid = threadIdx.x >> 6;
  int lane = threadIdx.x & 63;
  int n = blockIdx.x * 4 + wid;
  if (n >= N) return;
  int L = lane & 31;
  int h = L >> 3;
  int base = rowptr[n], end = rowptr[n + 1];
  float er = Pdst[n * 8 + 4 + h];
  float s = 0.f, a0 = 0.f, a1 = 0.f, a2 = 0.f, a3 = 0.f;
  int j = base + (lane >> 5);
  int sn = (j < end) ? srcs[j] : 0;
  while (j < end) {
    int jn = j + 2;
    int sn_next = (jn < end) ? srcs[jn] : 0;   // prefetch next addr root
    float x = Psrc[sn * 8 + h] + er + eec[j * 4 + h];
    x = (x > 0.f) ? x : NEG * x;
    ushort4 f = *(const ushort4*)(fsb + (size_t)sn * HID + L * 4);
    float w = __expf(x);
    s += w;
    a0 += w * b2f(f.x);
    a1 += w * b2f(f.y);
    a2 += w * b2f(f.z);
    a3 += w * b2f(f.w);
    j = jn;
    sn = sn_next;
  }
  // merge the two half-wave partitions (even/odd edges)
  s  += __shfl_xor(s, 32);
  a0 += __shfl_xor(a0, 32);
  a1 += __shfl_xor(a1, 32);
  a2 += __shfl_xor(a2, 32);
  a3 += __shfl_xor(a3, 32);
  if (lane < 32) {
    float inv = 1.f / (s + 1e-9f);
    a0 *= inv; a1 *= inv; a2 *= inv; a3 *= inv;
    if (RELU) {
      a0 = fmaxf(a0, 0.f); a1 = fmaxf(a1, 0.f);
      a2 = fmaxf(a2, 0.f); a3 = fmaxf(a3, 0.f);
    }
    *(float4*)(out + (size_t)n * HID + L * 4) = make_float4(a0, a1, a2, a3);
  }
}

// ----------------------------- host side -----------------------------
extern "C" void kernel_launch(void* const* d_in, const int* in_sizes, int n_in,
                              void* d_out, int out_size, void* d_ws, size_t ws_size,
                              hipStream_t stream) {
  const float* X_user = (const float*)d_in[0];
  const float* X_item = (const float*)d_in[1];
  const float* Ef_ui[2] = {(const float*)d_in[2], (const float*)d_in[4]};
  const float* Ef_iu[2] = {(const float*)d_in[3], (const float*)d_in[5]};
  const float* Wp[2][2];  const float* Wep[2][2];
  const float* alp[2][2]; const float* arp[2][2]; const float* aep[2][2];
  for (int l = 0; l < 2; ++l)
    for (int et = 0; et < 2; ++et) {
      int b = 6 + (l * 2 + et) * 5;
      Wp[l][et]  = (const float*)d_in[b + 0];
      Wep[l][et] = (const float*)d_in[b + 1];
      alp[l][et] = (const float*)d_in[b + 2];
      arp[l][et] = (const float*)d_in[b + 3];
      aep[l][et] = (const float*)d_in[b + 4];
    }
  const int* src_ui = (const int*)d_in[26];
  const int* dst_ui = (const int*)d_in[27];
  const int* src_iu = (const int*)d_in[28];
  const int* dst_iu = (const int*)d_in[29];

  const int N = in_sizes[0] / HID;  // 50000
  const int E = in_sizes[26];       // 500000

  // ---- workspace carve-up ----
  char* w = (char*)d_ws;
  size_t off = 0;
  auto carve = [&](size_t bytes) {
    off = (off + 255) & ~(size_t)255;
    char* p = w + off;
    off += bytes;
    return p;
  };
  int* rowptr_ui = (int*)carve((N + 1) * 4);
  int* rowptr_iu = (int*)carve((N + 1) * 4);
  int* eidx_ui = (int*)carve((size_t)E * 4);
  int* eidx_iu = (int*)carve((size_t)E * 4);
  int* srcs_ui = (int*)carve((size_t)E * 4);
  int* srcs_iu = (int*)carve((size_t)E * 4);
  int* cnt_blk = (int*)carve((size_t)4 * N * 4);
  int* cnt_ui = cnt_blk, *cnt_iu = cnt_blk + N, *fill_ui = cnt_blk + 2 * N, *fill_iu = cnt_blk + 3 * N;
  int* bsum_ui = (int*)carve(256 * 4);
  int* bsum_iu = (int*)carve(256 * 4);
  float* P_user = (float*)carve((size_t)N * 8 * 4);
  float* P_item = (float*)carve((size_t)N * 8 * 4);
  float* eec_ui = (float*)carve((size_t)E * 4 * 4);
  float* eec_iu = (float*)carve((size_t)E * 4 * 4);
  unsigned short* fs_a = (unsigned short*)carve((size_t)N * HID * 2);  // bf16
  unsigned short* fs_b = (unsigned short*)carve((size_t)N * HID * 2);  // bf16
  float* h_u1 = (float*)carve((size_t)N * HID * 4);
  float* h_i1 = (float*)carve((size_t)N * HID * 4);
  float* Vl_u = (float*)carve(HID * 4 * 4);
  float* Vr_u = (float*)carve(HID * 4 * 4);
  float* Vl_i = (float*)carve(HID * 4 * 4);
  float* Vr_i = (float*)carve(HID * 4 * 4);
  float* Ve_ui = (float*)carve(FE * 4 * 4);
  float* Ve_iu = (float*)carve(FE * 4 * 4);

  const int nbE = (E + 255) / 256;
  const int nbN = (N + 255) / 256;

  // ---- CSR build (once; shared by both layers) ----
  k_zero_i32<<<(4 * N + 255) / 256, 256, 0, stream>>>(cnt_blk, 4 * N);
  k_hist<<<nbE, 256, 0, stream>>>(dst_ui, cnt_ui, E);
  k_hist<<<nbE, 256, 0, stream>>>(dst_iu, cnt_iu, E);
  k_scanA<<<nbN, 256, 0, stream>>>(cnt_ui, bsum_ui, N);
  k_scanA<<<nbN, 256, 0, stream>>>(cnt_iu, bsum_iu, N);
  k_scanB<<<1, 256, 0, stream>>>(bsum_ui, nbN);
  k_scanB<<<1, 256, 0, stream>>>(bsum_iu, nbN);
  k_scanC<<<nbN, 256, 0, stream>>>(cnt_ui, bsum_ui, rowptr_ui, N);
  k_scanC<<<nbN, 256, 0, stream>>>(cnt_iu, bsum_iu, rowptr_iu, N);
  k_scatter<<<nbE, 256, 0, stream>>>(dst_ui, src_ui, rowptr_ui, fill_ui, eidx_ui, srcs_ui, E);
  k_scatter<<<nbE, 256, 0, stream>>>(dst_iu, src_iu, rowptr_iu, fill_iu, eidx_iu, srcs_iu, E);

  // ---- layers ----
  for (int l = 0; l < 2; ++l) {
    const float* Xu = (l == 0) ? X_user : h_u1;
    const float* Xi = (l == 0) ? X_item : h_i1;
    VJobs jb;
    jb.j[0] = {Wp[l][0], alp[l][0], Vl_u, HID};  // el for users as src (ui)
    jb.j[1] = {Wp[l][1], arp[l][1], Vr_u, HID};  // er for users as dst (iu)
    jb.j[2] = {Wp[l][1], alp[l][1], Vl_i, HID};  // el for items as src (iu)
    jb.j[3] = {Wp[l][0], arp[l][0], Vr_i, HID};  // er for items as dst (ui)
    jb.j[4] = {Wep[l][0], aep[l][0], Ve_ui, FE};
    jb.j[5] = {Wep[l][1], aep[l][1], Ve_iu, FE};
    k_makev<<<6, 128, 0, stream>>>(jb);

    k_proj<<<(N * 8 + 255) / 256, 256, 0, stream>>>(Xu, Vl_u, Vr_u, P_user, N);
    k_proj<<<(N * 8 + 255) / 256, 256, 0, stream>>>(Xi, Vl_i, Vr_i, P_item, N);
    k_ee<<<nbE, 256, 0, stream>>>(Ef_ui[l], Ve_ui, eidx_ui, eec_ui, E);
    k_ee<<<nbE, 256, 0, stream>>>(Ef_iu[l], Ve_iu, eidx_iu, eec_iu, E);
    k_gemm<<<(N + BM - 1) / BM, 256, 0, stream>>>(Xu, Wp[l][0], fs_a, N);
    k_gemm<<<(N + BM - 1) / BM, 256, 0, stream>>>(Xi, Wp[l][1], fs_b, N);

    float* out_ui = (l == 0) ? h_i1 : ((float*)d_out + (size_t)N * HID);  // hi2 second
    float* out_iu = (l == 0) ? h_u1 : (float*)d_out;                      // hu2 first
    int aggGrid = (N + 3) / 4;
    if (l == 0) {
      k_agg<true><<<aggGrid, 256, 0, stream>>>(rowptr_ui, srcs_ui, P_user, P_item,
                                               eec_ui, fs_a, out_ui, N);
      k_agg<true><<<aggGrid, 256, 0, stream>>>(rowptr_iu, srcs_iu, P_item, P_user,
                                               eec_iu, fs_b, out_iu, N);
    } else {
      k_agg<false><<<aggGrid, 256, 0, stream>>>(rowptr_ui, srcs_ui, P_user, P_item,
                                                eec_ui, fs_a, out_ui, N);
      k_agg<false><<<aggGrid, 256, 0, stream>>>(rowptr_iu, srcs_iu, P_item, P_user,
                                                eec_iu, fs_b, out_iu, N);
    }
  }
}

// Round 5
// 662.055 us; speedup vs baseline: 1.4098x; 1.1529x over previous
//
#include <hip/hip_runtime.h>
#include <cstdint>

#define HH 4
#define DD 32
#define HID 128
#define FE 16
#define NEG 0.2f

// ----------------------------- small utils -----------------------------
__global__ void k_zero_i32(int* __restrict__ p, int n) {
  int i = blockIdx.x * blockDim.x + threadIdx.x;
  if (i < n) p[i] = 0;
}

__device__ inline unsigned short f2b(float x) {  // f32 -> bf16 RNE
  unsigned int u = __float_as_uint(x);
  u = (u + 0x7fffu + ((u >> 16) & 1u)) >> 16;
  return (unsigned short)u;
}
__device__ inline float lo2f(unsigned int p) { return __uint_as_float(p << 16); }
__device__ inline float hi2f(unsigned int p) { return __uint_as_float(p & 0xffff0000u); }

// ----------------------------- CSR build (merged ui/iu via blockIdx.y) ---
__global__ void k_hist2(const int* __restrict__ d0, const int* __restrict__ d1,
                        int* __restrict__ c0, int* __restrict__ c1, int E) {
  const int* dst = blockIdx.y ? d1 : d0;
  int* cnt = blockIdx.y ? c1 : c0;
  int i = blockIdx.x * blockDim.x + threadIdx.x;
  if (i < E) atomicAdd(&cnt[dst[i]], 1);
}

__global__ void k_scanA2(int* __restrict__ c0, int* __restrict__ c1,
                         int* __restrict__ b0, int* __restrict__ b1, int N) {
  int* cnt = blockIdx.y ? c1 : c0;
  int* bsum = blockIdx.y ? b1 : b0;
  __shared__ int sh[256];
  int t = threadIdx.x, i = blockIdx.x * 256 + t;
  int v = (i < N) ? cnt[i] : 0;
  sh[t] = v;
  __syncthreads();
  for (int off = 1; off < 256; off <<= 1) {
    int add = (t >= off) ? sh[t - off] : 0;
    __syncthreads();
    sh[t] += add;
    __syncthreads();
  }
  if (i < N) cnt[i] = sh[t];
  if (t == 255) bsum[blockIdx.x] = sh[255];
}

__global__ void k_scanB2(int* __restrict__ b0, int* __restrict__ b1, int nb) {
  int* bsum = blockIdx.y ? b1 : b0;
  __shared__ int sh[256];
  int t = threadIdx.x;
  int v = (t < nb) ? bsum[t] : 0;
  sh[t] = v;
  __syncthreads();
  for (int off = 1; off < 256; off <<= 1) {
    int add = (t >= off) ? sh[t - off] : 0;
    __syncthreads();
    sh[t] += add;
    __syncthreads();
  }
  if (t < nb) bsum[t] = sh[t] - v;  // exclusive
}

__global__ void k_scanC2(const int* __restrict__ c0, const int* __restrict__ c1,
                         const int* __restrict__ b0, const int* __restrict__ b1,
                         int* __restrict__ r0, int* __restrict__ r1, int N) {
  const int* cnt = blockIdx.y ? c1 : c0;
  const int* bsum = blockIdx.y ? b1 : b0;
  int* rowptr = blockIdx.y ? r1 : r0;
  int i = blockIdx.x * blockDim.x + threadIdx.x;
  if (i < N) rowptr[i + 1] = cnt[i] + bsum[i >> 8];
  if (i == 0) rowptr[0] = 0;
}

struct ScatArgs {
  const int* dst; const int* src; const int* rowptr;
  int* fill; int* eidx; int* srcs;
};

__global__ void k_scatter2(ScatArgs s0, ScatArgs s1, int E) {
  ScatArgs S = blockIdx.y ? s1 : s0;
  int i = blockIdx.x * blockDim.x + threadIdx.x;
  if (i < E) {
    int d = S.dst[i];
    int pos = S.rowptr[d] + atomicAdd(&S.fill[d], 1);
    S.eidx[pos] = i;
    S.srcs[pos] = S.src[i];
  }
}

// ----------------------------- tiny V projections -----------------------------
struct VJob { const float* W; const float* a; float* V; int K; };
struct VJobs { VJob j[6]; };

__global__ void k_makev(VJobs P) {
  VJob job = P.j[blockIdx.x];
  int t = threadIdx.x;  // 128 threads
  if (t < job.K) {
    for (int h = 0; h < HH; ++h) {
      const float* wrow = job.W + t * HID + h * DD;
      const float* ar = job.a + h * DD;
      float s = 0.f;
      for (int d = 0; d < DD; ++d) s += wrow[d] * ar[d];
      job.V[t * HH + h] = s;
    }
  }
}

// P[n][0:4] = X[n] @ Vl, P[n][4:8] = X[n] @ Vr  (merged pair; BIN: bf16 input)
template <bool BIN>
__global__ void k_proj2(const void* __restrict__ X0, const float* __restrict__ Vl0,
                        const float* __restrict__ Vr0, float* __restrict__ P0,
                        const void* __restrict__ X1, const float* __restrict__ Vl1,
                        const float* __restrict__ Vr1, float* __restrict__ P1, int N) {
  const void* X = blockIdx.y ? X1 : X0;
  const float* Vl = blockIdx.y ? Vl1 : Vl0;
  const float* Vr = blockIdx.y ? Vr1 : Vr0;
  float* P = blockIdx.y ? P1 : P0;
  int idx = blockIdx.x * blockDim.x + threadIdx.x;
  if (idx >= N * 8) return;
  int n = idx >> 3, j = idx & 7;
  const float* V = (j < 4) ? Vl : Vr;
  int jj = j & 3;
  float acc = 0.f;
  if (BIN) {
    const unsigned short* xp = (const unsigned short*)X + (size_t)n * HID;
#pragma unroll
    for (int c = 0; c < 16; ++c) {
      uint4 u = *(const uint4*)(xp + c * 8);
      const float* vb = V + c * 8 * 4 + jj;
      acc += lo2f(u.x) * vb[0]  + hi2f(u.x) * vb[4];
      acc += lo2f(u.y) * vb[8]  + hi2f(u.y) * vb[12];
      acc += lo2f(u.z) * vb[16] + hi2f(u.z) * vb[20];
      acc += lo2f(u.w) * vb[24] + hi2f(u.w) * vb[28];
    }
  } else {
    const float4* x4 = (const float4*)((const float*)X + (size_t)n * HID);
#pragma unroll 8
    for (int k4 = 0; k4 < 32; ++k4) {
      float4 x = x4[k4];
      const float* vb = V + k4 * 16 + jj;
      acc += x.x * vb[0] + x.y * vb[4] + x.z * vb[8] + x.w * vb[12];
    }
  }
  P[idx] = acc;
}

// eec[j][h] = Ef[eidx[j], 0:16] @ Ve[16][4]   (CSR order, merged pair)
__global__ void k_ee2(const float* __restrict__ Ef0, const float* __restrict__ Ve0,
                      const int* __restrict__ ei0, float* __restrict__ ec0,
                      const float* __restrict__ Ef1, const float* __restrict__ Ve1,
                      const int* __restrict__ ei1, float* __restrict__ ec1, int E) {
  const float* Ef = blockIdx.y ? Ef1 : Ef0;
  const float* Ve = blockIdx.y ? Ve1 : Ve0;
  const int* eidx = blockIdx.y ? ei1 : ei0;
  float* eec = blockIdx.y ? ec1 : ec0;
  int j = blockIdx.x * blockDim.x + threadIdx.x;
  if (j >= E) return;
  int e = eidx[j];
  const float4* f4 = (const float4*)(Ef + (size_t)e * FE);
  float a0 = 0.f, a1 = 0.f, a2 = 0.f, a3 = 0.f;
#pragma unroll
  for (int k4 = 0; k4 < 4; ++k4) {
    float4 x = f4[k4];
    const float* v = Ve + k4 * 16;
    a0 += x.x * v[0] + x.y * v[4] + x.z * v[8]  + x.w * v[12];
    a1 += x.x * v[1] + x.y * v[5] + x.z * v[9]  + x.w * v[13];
    a2 += x.x * v[2] + x.y * v[6] + x.z * v[10] + x.w * v[14];
    a3 += x.x * v[3] + x.y * v[7] + x.z * v[11] + x.w * v[15];
  }
  ((float4*)eec)[j] = make_float4(a0, a1, a2, a3);
}

// ----------------------------- fs GEMM (f32 math, bf16 out, merged pair) ----
// KC=32 chunks: LDS 24 KB -> ~5-6 blocks/CU. A read via b128 broadcast.
#define BM 64
#define KC 32
template <bool BIN>
__global__ __launch_bounds__(256) void k_gemm2(
    const void* __restrict__ X0, const float* __restrict__ W0, unsigned short* __restrict__ o0,
    const void* __restrict__ X1, const float* __restrict__ W1, unsigned short* __restrict__ o1,
    int N) {
  const void* X = blockIdx.y ? X1 : X0;
  const float* W = blockIdx.y ? W1 : W0;
  unsigned short* outb = blockIdx.y ? o1 : o0;
  __shared__ float Xs[BM][KC];    // 8 KB
  __shared__ float Ws[KC][HID];   // 16 KB
  int t = threadIdx.x;
  int bm = blockIdx.x * BM;
  int rg = t >> 5;   // 8 row groups of 8 rows
  int cg = t & 31;   // cols cg, cg+32, cg+64, cg+96
  float acc[8][4] = {};
  for (int kc = 0; kc < HID; kc += KC) {
    // stage X tile 64x32
    if (BIN) {
      int r = t >> 2, c8 = (t & 3) * 8;
      int gr = bm + r; if (gr >= N) gr = N - 1;
      uint4 u = *(const uint4*)((const unsigned short*)X + (size_t)gr * HID + kc + c8);
      float* xr = &Xs[r][c8];
      xr[0] = lo2f(u.x); xr[1] = hi2f(u.x);
      xr[2] = lo2f(u.y); xr[3] = hi2f(u.y);
      xr[4] = lo2f(u.z); xr[5] = hi2f(u.z);
      xr[6] = lo2f(u.w); xr[7] = hi2f(u.w);
    } else {
#pragma unroll
      for (int i = t; i < BM * KC / 4; i += 256) {
        int r = i >> 3, c4 = (i & 7) * 4;
        int gr = bm + r; if (gr >= N) gr = N - 1;
        *(float4*)&Xs[r][c4] = *(const float4*)((const float*)X + (size_t)gr * HID + kc + c4);
      }
    }
    // stage W tile 32x128
#pragma unroll
    for (int i = t; i < KC * HID / 4; i += 256) {
      int r = i >> 5, c4 = (i & 31) * 4;
      *(float4*)&Ws[r][c4] = *(const float4*)(W + (size_t)(kc + r) * HID + c4);
    }
    __syncthreads();
#pragma unroll
    for (int k4 = 0; k4 < KC / 4; ++k4) {
      float bv[4][4];
#pragma unroll
      for (int kk = 0; kk < 4; ++kk) {
        bv[kk][0] = Ws[k4 * 4 + kk][cg];
        bv[kk][1] = Ws[k4 * 4 + kk][cg + 32];
        bv[kk][2] = Ws[k4 * 4 + kk][cg + 64];
        bv[kk][3] = Ws[k4 * 4 + kk][cg + 96];
      }
#pragma unroll
      for (int i = 0; i < 8; ++i) {
        float4 a4 = *(const float4*)&Xs[rg * 8 + i][k4 * 4];
        float av[4] = {a4.x, a4.y, a4.z, a4.w};
#pragma unroll
        for (int kk = 0; kk < 4; ++kk)
#pragma unroll
          for (int jj = 0; jj < 4; ++jj)
            acc[i][jj] += av[kk] * bv[kk][jj];
      }
    }
    __syncthreads();
  }
#pragma unroll
  for (int i = 0; i < 8; ++i) {
    int gr = bm + rg * 8 + i;
    if (gr < N) {
      unsigned short* o = outb + (size_t)gr * HID;
      o[cg]      = f2b(acc[i][0]);
      o[cg + 32] = f2b(acc[i][1]);
      o[cg + 64] = f2b(acc[i][2]);
      o[cg + 96] = f2b(acc[i][3]);
    }
  }
}

// ----------------------------- per-dst aggregation (merged pair) -----------
// one wave per dst node; quarter-wave per edge (4 edges/iter); lane owns 8 elems
// (one 16B uint4 gather). fs-row prefetch pipelines the gather latency.
struct AggArgs {
  const int* rowptr; const int* srcs;
  const float* Ps; const float* Pd; const float* eec;
  const unsigned short* fsb; void* out;
};

template <bool FINAL>  // FINAL: f32 out, no relu.  else: bf16 out, relu.
__global__ __launch_bounds__(256) void k_agg2(AggArgs a0, AggArgs a1, int N) {
  AggArgs A = blockIdx.y ? a1 : a0;
  int wid = threadIdx.x >> 6;
  int lane = threadIdx.x & 63;
  int n = blockIdx.x * 4 + wid;
  if (n >= N) return;
  int q = lane >> 4;   // quarter 0..3 -> edge offset
  int L = lane & 15;   // owns elems L*8 .. L*8+7
  int h = L >> 2;      // head
  int base = A.rowptr[n], end = A.rowptr[n + 1];
  float er = A.Pd[n * 8 + 4 + h];
  float s = 0.f;
  float c0 = 0.f, c1 = 0.f, c2 = 0.f, c3 = 0.f, c4 = 0.f, c5 = 0.f, c6 = 0.f, c7 = 0.f;
  int j = base + q;
  int sn = 0;
  uint4 f = {};
  if (j < end) {
    sn = A.srcs[j];
    f = *(const uint4*)(A.fsb + (size_t)sn * HID + L * 8);
  }
  while (j < end) {
    int jn = j + 4;
    int snn = 0;
    uint4 g = {};
    if (jn < end) {
      snn = A.srcs[jn];
      g = *(const uint4*)(A.fsb + (size_t)snn * HID + L * 8);
    }
    float x = A.Ps[sn * 8 + h] + er + A.eec[j * 4 + h];
    x = (x > 0.f) ? x : NEG * x;
    float w = __expf(x);
    s += w;
    c0 += w * lo2f(f.x); c1 += w * hi2f(f.x);
    c2 += w * lo2f(f.y); c3 += w * hi2f(f.y);
    c4 += w * lo2f(f.z); c5 += w * hi2f(f.z);
    c6 += w * lo2f(f.w); c7 += w * hi2f(f.w);
    j = jn; sn = snn; f = g;
  }
  // merge 4 quarter-partitions
  s  += __shfl_xor(s, 16);  s  += __shfl_xor(s, 32);
  c0 += __shfl_xor(c0, 16); c0 += __shfl_xor(c0, 32);
  c1 += __shfl_xor(c1, 16); c1 += __shfl_xor(c1, 32);
  c2 += __shfl_xor(c2, 16); c2 += __shfl_xor(c2, 32);
  c3 += __shfl_xor(c3, 16); c3 += __shfl_xor(c3, 32);
  c4 += __shfl_xor(c4, 16); c4 += __shfl_xor(c4, 32);
  c5 += __shfl_xor(c5, 16); c5 += __shfl_xor(c5, 32);
  c6 += __shfl_xor(c6, 16); c6 += __shfl_xor(c6, 32);
  c7 += __shfl_xor(c7, 16); c7 += __shfl_xor(c7, 32);
  if (lane < 16) {
    float inv = 1.f / (s + 1e-9f);
    c0 *= inv; c1 *= inv; c2 *= inv; c3 *= inv;
    c4 *= inv; c5 *= inv; c6 *= inv; c7 *= inv;
    if (FINAL) {
      float* op = (float*)A.out + (size_t)n * HID + L * 8;
      *(float4*)op = make_float4(c0, c1, c2, c3);
      *(float4*)(op + 4) = make_float4(c4, c5, c6, c7);
    } else {
      c0 = fmaxf(c0, 0.f); c1 = fmaxf(c1, 0.f); c2 = fmaxf(c2, 0.f); c3 = fmaxf(c3, 0.f);
      c4 = fmaxf(c4, 0.f); c5 = fmaxf(c5, 0.f); c6 = fmaxf(c6, 0.f); c7 = fmaxf(c7, 0.f);
      unsigned short* op = (unsigned short*)A.out + (size_t)n * HID + L * 8;
      ushort4 u0 = {f2b(c0), f2b(c1), f2b(c2), f2b(c3)};
      ushort4 u1 = {f2b(c4), f2b(c5), f2b(c6), f2b(c7)};
      *(ushort4*)op = u0;
      *(ushort4*)(op + 4) = u1;
    }
  }
}

// ----------------------------- host side -----------------------------
extern "C" void kernel_launch(void* const* d_in, const int* in_sizes, int n_in,
                              void* d_out, int out_size, void* d_ws, size_t ws_size,
                              hipStream_t stream) {
  const float* X_user = (const float*)d_in[0];
  const float* X_item = (const float*)d_in[1];
  const float* Ef_ui[2] = {(const float*)d_in[2], (const float*)d_in[4]};
  const float* Ef_iu[2] = {(const float*)d_in[3], (const float*)d_in[5]};
  const float* Wp[2][2];  const float* Wep[2][2];
  const float* alp[2][2]; const float* arp[2][2]; const float* aep[2][2];
  for (int l = 0; l < 2; ++l)
    for (int et = 0; et < 2; ++et) {
      int b = 6 + (l * 2 + et) * 5;
      Wp[l][et]  = (const float*)d_in[b + 0];
      Wep[l][et] = (const float*)d_in[b + 1];
      alp[l][et] = (const float*)d_in[b + 2];
      arp[l][et] = (const float*)d_in[b + 3];
      aep[l][et] = (const float*)d_in[b + 4];
    }
  const int* src_ui = (const int*)d_in[26];
  const int* dst_ui = (const int*)d_in[27];
  const int* src_iu = (const int*)d_in[28];
  const int* dst_iu = (const int*)d_in[29];

  const int N = in_sizes[0] / HID;  // 50000
  const int E = in_sizes[26];       // 500000

  // ---- workspace carve-up ----
  char* w = (char*)d_ws;
  size_t off = 0;
  auto carve = [&](size_t bytes) {
    off = (off + 255) & ~(size_t)255;
    char* p = w + off;
    off += bytes;
    return p;
  };
  int* rowptr_ui = (int*)carve((N + 1) * 4);
  int* rowptr_iu = (int*)carve((N + 1) * 4);
  int* eidx_ui = (int*)carve((size_t)E * 4);
  int* eidx_iu = (int*)carve((size_t)E * 4);
  int* srcs_ui = (int*)carve((size_t)E * 4);
  int* srcs_iu = (int*)carve((size_t)E * 4);
  int* cnt_blk = (int*)carve((size_t)4 * N * 4);
  int* cnt_ui = cnt_blk, *cnt_iu = cnt_blk + N, *fill_ui = cnt_blk + 2 * N, *fill_iu = cnt_blk + 3 * N;
  int* bsum_ui = (int*)carve(256 * 4);
  int* bsum_iu = (int*)carve(256 * 4);
  float* P_user = (float*)carve((size_t)N * 8 * 4);
  float* P_item = (float*)carve((size_t)N * 8 * 4);
  float* eec_ui = (float*)carve((size_t)E * 4 * 4);
  float* eec_iu = (float*)carve((size_t)E * 4 * 4);
  unsigned short* fs_a = (unsigned short*)carve((size_t)N * HID * 2);  // bf16
  unsigned short* fs_b = (unsigned short*)carve((size_t)N * HID * 2);  // bf16
  unsigned short* h_u1 = (unsigned short*)carve((size_t)N * HID * 2);  // bf16
  unsigned short* h_i1 = (unsigned short*)carve((size_t)N * HID * 2);  // bf16
  float* Vl_u = (float*)carve(HID * 4 * 4);
  float* Vr_u = (float*)carve(HID * 4 * 4);
  float* Vl_i = (float*)carve(HID * 4 * 4);
  float* Vr_i = (float*)carve(HID * 4 * 4);
  float* Ve_ui = (float*)carve(FE * 4 * 4);
  float* Ve_iu = (float*)carve(FE * 4 * 4);

  const int nbE = (E + 255) / 256;
  const int nbN = (N + 255) / 256;
  dim3 g2E(nbE, 2), g2N(nbN, 2);

  // ---- CSR build (once; shared by both layers) ----
  k_zero_i32<<<(4 * N + 255) / 256, 256, 0, stream>>>(cnt_blk, 4 * N);
  k_hist2<<<g2E, 256, 0, stream>>>(dst_ui, dst_iu, cnt_ui, cnt_iu, E);
  k_scanA2<<<g2N, 256, 0, stream>>>(cnt_ui, cnt_iu, bsum_ui, bsum_iu, N);
  k_scanB2<<<dim3(1, 2), 256, 0, stream>>>(bsum_ui, bsum_iu, nbN);
  k_scanC2<<<g2N, 256, 0, stream>>>(cnt_ui, cnt_iu, bsum_ui, bsum_iu, rowptr_ui, rowptr_iu, N);
  ScatArgs s0 = {dst_ui, src_ui, rowptr_ui, fill_ui, eidx_ui, srcs_ui};
  ScatArgs s1 = {dst_iu, src_iu, rowptr_iu, fill_iu, eidx_iu, srcs_iu};
  k_scatter2<<<g2E, 256, 0, stream>>>(s0, s1, E);

  // ---- layers ----
  for (int l = 0; l < 2; ++l) {
    const void* Xu = (l == 0) ? (const void*)X_user : (const void*)h_u1;
    const void* Xi = (l == 0) ? (const void*)X_item : (const void*)h_i1;
    VJobs jb;
    jb.j[0] = {Wp[l][0], alp[l][0], Vl_u, HID};  // el for users as src (ui)
    jb.j[1] = {Wp[l][1], arp[l][1], Vr_u, HID};  // er for users as dst (iu)
    jb.j[2] = {Wp[l][1], alp[l][1], Vl_i, HID};  // el for items as src (iu)
    jb.j[3] = {Wp[l][0], arp[l][0], Vr_i, HID};  // er for items as dst (ui)
    jb.j[4] = {Wep[l][0], aep[l][0], Ve_ui, FE};
    jb.j[5] = {Wep[l][1], aep[l][1], Ve_iu, FE};
    k_makev<<<6, 128, 0, stream>>>(jb);

    dim3 gp((N * 8 + 255) / 256, 2);
    dim3 gg((N + BM - 1) / BM, 2);
    dim3 ga((N + 3) / 4, 2);
    if (l == 0) {
      k_proj2<false><<<gp, 256, 0, stream>>>(Xu, Vl_u, Vr_u, P_user, Xi, Vl_i, Vr_i, P_item, N);
    } else {
      k_proj2<true><<<gp, 256, 0, stream>>>(Xu, Vl_u, Vr_u, P_user, Xi, Vl_i, Vr_i, P_item, N);
    }
    k_ee2<<<g2E, 256, 0, stream>>>(Ef_ui[l], Ve_ui, eidx_ui, eec_ui,
                                   Ef_iu[l], Ve_iu, eidx_iu, eec_iu, E);
    if (l == 0) {
      k_gemm2<false><<<gg, 256, 0, stream>>>(Xu, Wp[l][0], fs_a, Xi, Wp[l][1], fs_b, N);
    } else {
      k_gemm2<true><<<gg, 256, 0, stream>>>(Xu, Wp[l][0], fs_a, Xi, Wp[l][1], fs_b, N);
    }

    // ui graph: dst = items ; iu graph: dst = users
    void* out_ui = (l == 0) ? (void*)h_i1 : (void*)((float*)d_out + (size_t)N * HID);
    void* out_iu = (l == 0) ? (void*)h_u1 : (void*)d_out;
    AggArgs aUI = {rowptr_ui, srcs_ui, P_user, P_item, eec_ui, fs_a, out_ui};
    AggArgs aIU = {rowptr_iu, srcs_iu, P_item, P_user, eec_iu, fs_b, out_iu};
    if (l == 0) {
      k_agg2<false><<<ga, 256, 0, stream>>>(aUI, aIU, N);
    } else {
      k_agg2<true><<<ga, 256, 0, stream>>>(aUI, aIU, N);
    }
  }
}